// Round 8
// baseline (730.766 us; speedup 1.0000x reference)
//
#include <hip/hip_runtime.h>
#include <hip/hip_bf16.h>
#include <math.h>

using bf16 = __hip_bfloat16;
typedef __bf16 bf16x8 __attribute__((ext_vector_type(8)));
typedef float f32x4 __attribute__((ext_vector_type(4)));
typedef unsigned int u32;

// B=2, D=8, H=56, W=56, C=384, NH=12, HD=32, WIN=(2,7,7), SHIFT=(1,3,3)
// N=98 tokens/window, 512 windows, rows = 50176

// windowed row -> global token index (window-reverse + roll)
__device__ __forceinline__ int row_to_gidx(int row) {
  int win = row / 98, tok = row - win * 98;
  int b = win >> 8, wd = (win >> 6) & 3, wh = (win >> 3) & 7, ww = win & 7;
  int td = tok / 49, rem = tok - td * 49;
  int th = rem / 7, tw = rem - th * 7;
  int od = (wd * 2 + td + 1) & 7;
  int oh = wh * 7 + th + 3; if (oh >= 56) oh -= 56;
  int ow = ww * 7 + tw + 3; if (ow >= 56) ow -= 56;
  return ((b * 8 + od) * 56 + oh) * 56 + ow;
}

// ---------------- AdaLN modulation ------------------------------------------
__global__ __launch_bounds__(256) void mod_kernel(
    const float* __restrict__ t, const float* __restrict__ w1,
    const float* __restrict__ w2, const float* __restrict__ b2,
    float* __restrict__ modout)
{
  __shared__ float u[2 * 48];
  int tid = threadIdx.x;
  if (tid < 96) {
    int b = tid / 48, r = tid - (tid / 48) * 48;
    float acc = 0.f;
    for (int k = 0; k < 384; ++k) {
      float x = t[b * 384 + k];
      float s = x / (1.f + __expf(-x));
      acc += s * w1[k * 48 + r];
    }
    u[b * 48 + r] = acc;
  }
  __syncthreads();
  for (int idx = tid; idx < 2 * 2304; idx += 256) {
    int b = idx / 2304, c = idx - b * 2304;
    float acc = b2[c];
    #pragma unroll
    for (int k = 0; k < 48; ++k) acc += u[b * 48 + k] * w2[k * 2304 + c];
    modout[idx] = acc;
  }
}

// -------- weight convert f32 (K,N) -> bf16 MFMA-fragment-major layout -------
// Block (ntile = n>>4, kstep = k>>5) of 16 cols x 32 ks stored as 512 bf16:
// lane l = (n&15) + ((k>>3)&3)*16 holds elems j = k&7 at [block*512 + l*8 + j].
__global__ __launch_bounds__(256) void wconv_frag_kernel(
    const float* __restrict__ W, bf16* __restrict__ Wf, int K, int N)
{
  int idx = blockIdx.x * 256 + threadIdx.x;
  if (idx >= K * N) return;
  int k = idx / N, n = idx - (idx / N) * N;
  int ntile = n >> 4, kstep = k >> 5;
  int l = (n & 15) + (((k >> 3) & 3) << 4);
  size_t dst = (((size_t)(ntile * (K >> 5) + kstep)) << 9) + (l << 3) + (k & 7);
  Wf[dst] = __float2bfloat16(W[idx]);
}

// ---------------- bias+mask table: bm[4][12][112][112] bf16 -----------------
__global__ __launch_bounds__(256) void bm_kernel(
    const float* __restrict__ relb, bf16* __restrict__ bm)
{
  int idx = blockIdx.x * 256 + threadIdx.x;
  if (idx >= 4 * 12 * 112 * 112) return;
  int j = idx % 112, tmp = idx / 112;
  int i = tmp % 112; tmp /= 112;
  int h = tmp % 12, p = tmp / 12;
  float v;
  if (i < 98 && j < 98) {
    int tdi = i / 49, ri = i % 49, thi = ri / 7, twi = ri % 7;
    int tdj = j / 49, rj = j % 49, thj = rj / 7, twj = rj % 7;
    int ridx = (tdi - tdj + 1) * 169 + (thi - thj + 6) * 13 + (twi - twj + 6);
    bool msk = ((p & 2) && (tdi != tdj)) || ((p & 1) && ((thi < 4) != (thj < 4)));
    v = relb[ridx * 12 + h] + (msk ? -100.f : 0.f);
  } else {
    v = -1e38f;
  }
  bm[idx] = __float2bfloat16(v);
}

// ---------------- LN + modulate ---------------------------------------------
template <int PHASE>
__global__ __launch_bounds__(256) void ln_mod_kernel(
    const float* __restrict__ src, const float* __restrict__ modv,
    bf16* __restrict__ dst)
{
  int wid = threadIdx.x >> 6, lane = threadIdx.x & 63;
  int row = blockIdx.x * 4 + wid;
  int gtok;
  if (PHASE == 0) gtok = row_to_gidx(row); else gtok = row;
  int b = row / 25088;
  const float* s = src + (size_t)gtok * 384;
  float vals[6], sum = 0.f, sq = 0.f;
  #pragma unroll
  for (int i = 0; i < 6; ++i) {
    float v = s[lane + i * 64];
    vals[i] = v; sum += v; sq += v * v;
  }
  #pragma unroll
  for (int o = 32; o; o >>= 1) { sum += __shfl_xor(sum, o, 64); sq += __shfl_xor(sq, o, 64); }
  float mean = sum * (1.f / 384.f);
  float var = sq * (1.f / 384.f) - mean * mean;
  float rstd = rsqrtf(var + 1e-6f);
  int mb = b * 2304 + (PHASE == 0 ? 0 : 1152);
  #pragma unroll
  for (int i = 0; i < 6; ++i) {
    int c = lane + i * 64;
    float scv = modv[mb + 384 + c], shv = modv[mb + c];
    dst[(size_t)row * 384 + c] = __float2bfloat16((vals[i] - mean) * rstd * (1.f + scv) + shv);
  }
}

// ---------------- 128x128 bf16 MFMA GEMM — ZERO LDS / ZERO BARRIERS ---------
// Each wave owns a 64x64 output tile fully independently. A fragments are
// loaded per-lane straight from row-major global (16x64B segments, 100%
// byte-efficient); B fragments are coalesced 1KB loads from the
// fragment-major weight layout. Register ping-pong double-buffers the next
// K-step's fragments under the current step's 16 MFMAs; the compiler's
// auto-waitcnt provides the fine-grained scheduling (no s_barrier at all).
template <int EPI>
__global__ __launch_bounds__(256) void gemm128_kernel(
    const bf16* __restrict__ A, const bf16* __restrict__ Bf,
    const float* __restrict__ bias, const int N, const int K,
    bf16* __restrict__ outB, float* __restrict__ outF,
    const float* __restrict__ resid, const float* __restrict__ modv)
{
  const int tid = threadIdx.x;
  const int lane = tid & 63, wid = tid >> 6;
  const int wm = wid >> 1, wn = wid & 1;

  // XCD-contiguous remap (nwg % 8 == 0 for all our grids)
  const int gx = gridDim.x;
  const int nwg = gx * (int)gridDim.y;
  const int orig = (int)blockIdx.y * gx + (int)blockIdx.x;
  const int q = nwg >> 3;
  const int wg = (orig & 7) * q + (orig >> 3);
  const int bx = wg % gx, by = wg / gx;
  const int row0 = by * 128, col0 = bx * 128;

  const int nK32 = K >> 5;

  // per-lane A base: row = row0 + wm*64 + (lane&15), k-slot = (lane>>4)*8
  const bf16* abase = A + (size_t)(row0 + wm * 64 + (lane & 15)) * K + ((lane >> 4) << 3);
  const size_t amstride = (size_t)16 * K;  // m-tile stride in elements
  // B base: ntile = col0/16 + wn*4 + n, lane-slot = lane*8
  const bf16* bbase = Bf + (((size_t)((col0 >> 4) + wn * 4) * nK32) << 9) + (lane << 3);
  const size_t bnstride = (size_t)nK32 << 9;  // n-tile stride in elements

  const f32x4 vzero = {0.f, 0.f, 0.f, 0.f};
  f32x4 acc[4][4];
  #pragma unroll
  for (int m = 0; m < 4; ++m)
    #pragma unroll
    for (int n = 0; n < 4; ++n) acc[m][n] = vzero;

  bf16x8 a0[4], b0[4], a1[4], b1[4];

#define LOAD_A(dst, t)                                                        \
  {                                                                           \
    _Pragma("unroll")                                                         \
    for (int m = 0; m < 4; ++m)                                               \
      dst[m] = *(const bf16x8*)(abase + m * amstride + (size_t)(t) * 32);     \
  }
#define LOAD_B(dst, t)                                                        \
  {                                                                           \
    _Pragma("unroll")                                                         \
    for (int n = 0; n < 4; ++n)                                               \
      dst[n] = *(const bf16x8*)(bbase + n * bnstride + ((size_t)(t) << 9));   \
  }
#define MFMA_STEP(aa, bb)                                                     \
  {                                                                           \
    _Pragma("unroll")                                                         \
    for (int m = 0; m < 4; ++m)                                               \
      _Pragma("unroll")                                                       \
      for (int n = 0; n < 4; ++n)                                             \
        acc[m][n] = __builtin_amdgcn_mfma_f32_16x16x32_bf16(aa[m], bb[n],     \
                                                            acc[m][n], 0, 0, 0); \
  }

  LOAD_A(a0, 0); LOAD_B(b0, 0);
  int t = 0;
  for (; t + 2 <= nK32; t += 2) {
    LOAD_A(a1, t + 1); LOAD_B(b1, t + 1);
    MFMA_STEP(a0, b0);
    if (t + 2 < nK32) { LOAD_A(a0, t + 2); LOAD_B(b0, t + 2); }
    MFMA_STEP(a1, b1);
  }
  if (t < nK32) { MFMA_STEP(a0, b0); }

#undef LOAD_A
#undef LOAD_B
#undef MFMA_STEP

  #pragma unroll
  for (int m = 0; m < 4; ++m) {
    #pragma unroll
    for (int r = 0; r < 4; ++r) {
      const int row = row0 + wm * 64 + m * 16 + (lane >> 4) * 4 + r;
      int gofs = 0, b = 0;
      if (EPI == 1) { gofs = row_to_gidx(row) * 384; b = row / 25088; }
      if (EPI == 3) { gofs = row * 384; b = row / 25088; }
      #pragma unroll
      for (int n = 0; n < 4; ++n) {
        const int col = col0 + wn * 64 + n * 16 + (lane & 15);
        float v = acc[m][n][r] + bias[col];
        if (EPI == 0) {
          outB[(size_t)row * N + col] = __float2bfloat16(v);
        } else if (EPI == 2) {
          float g = 0.5f * v * (1.f + erff(v * 0.70710678118654752f));
          outB[(size_t)row * N + col] = __float2bfloat16(g);
        } else if (EPI == 1) {
          outF[gofs + col] = resid[gofs + col] + modv[b * 2304 + 768 + col] * v;
        } else {
          outF[gofs + col] = resid[gofs + col] + modv[b * 2304 + 1920 + col] * v;
        }
      }
    }
  }
}

// ---------------- MFMA window attention: block = (head, window) -------------
__global__ __launch_bounds__(256) void attn_kernel(
    const bf16* __restrict__ qkv, const bf16* __restrict__ bm,
    bf16* __restrict__ outp)
{
  __shared__ bf16 k_s[112][40];      // [token][d], zero rows >=98
  __shared__ bf16 v_t[32][136];      // [d][token], zero tokens 98..127
  __shared__ bf16 p_s[4][16][136];   // per-wave P strip, cols 112..135 zeroed

  const int head = blockIdx.x;
  const int win = blockIdx.y;
  const int tid = threadIdx.x;
  const int lane = tid & 63, wid = tid >> 6;
  const int g = lane >> 4, c16 = lane & 15;
  const size_t rowbase = (size_t)win * 98;
  const bf16 zero = __float2bfloat16(0.f);

  for (int lin = tid; lin < 448; lin += 256) {
    int row = lin >> 2, ch = (lin & 3) << 3;
    uint4 val = make_uint4(0, 0, 0, 0);
    if (row < 98)
      val = *(const uint4*)(qkv + (rowbase + row) * 1152 + 384 + head * 32 + ch);
    *(uint4*)&k_s[row][ch] = val;
  }
  for (int lin = tid; lin < 4096; lin += 256) {
    int d = lin & 31, tok = lin >> 5;
    bf16 val = zero;
    if (tok < 98) val = qkv[(rowbase + tok) * 1152 + 768 + head * 32 + d];
    v_t[d][tok] = val;
  }
  for (int lin = tid; lin < 1536; lin += 256) {
    int w = lin / 384, rem = lin - w * 384;
    p_s[w][rem / 24][112 + rem % 24] = zero;
  }
  __syncthreads();

  const int p = ((((win >> 6) & 3) == 3) ? 2 : 0) | ((((win >> 3) & 7) == 7) ? 1 : 0);
  const bf16* bmrow = bm + (size_t)(p * 12 + head) * 12544;
  const float scale = 0.17677669529663687f;  // 1/sqrt(32)
  const f32x4 vzero = {0.f, 0.f, 0.f, 0.f};

  for (int s = wid; s < 7; s += 4) {
    const int q0 = s * 16;
    int qrow = q0 + c16; if (qrow > 97) qrow = 97;
    bf16x8 qf = *(const bf16x8*)(qkv + (rowbase + qrow) * 1152 + head * 32 + g * 8);

    f32x4 sa[7];
    #pragma unroll
    for (int ct = 0; ct < 7; ++ct) {
      bf16x8 kf = *(const bf16x8*)&k_s[ct * 16 + c16][g * 8];
      sa[ct] = __builtin_amdgcn_mfma_f32_16x16x32_bf16(qf, kf, vzero, 0, 0, 0);
    }

    float sv[7][4];
    float mrow[4] = {-1e30f, -1e30f, -1e30f, -1e30f};
    #pragma unroll
    for (int ct = 0; ct < 7; ++ct) {
      #pragma unroll
      for (int r = 0; r < 4; ++r) {
        int i = q0 + g * 4 + r, j = ct * 16 + c16;
        float val = sa[ct][r] * scale + __bfloat162float(bmrow[i * 112 + j]);
        sv[ct][r] = val;
        mrow[r] = fmaxf(mrow[r], val);
      }
    }
    #pragma unroll
    for (int r = 0; r < 4; ++r) {
      #pragma unroll
      for (int off = 1; off < 16; off <<= 1)
        mrow[r] = fmaxf(mrow[r], __shfl_xor(mrow[r], off, 64));
    }
    float rsum[4] = {0.f, 0.f, 0.f, 0.f};
    #pragma unroll
    for (int ct = 0; ct < 7; ++ct) {
      #pragma unroll
      for (int r = 0; r < 4; ++r) {
        float e = __expf(sv[ct][r] - mrow[r]);
        sv[ct][r] = e;
        rsum[r] += e;
      }
    }
    #pragma unroll
    for (int r = 0; r < 4; ++r) {
      #pragma unroll
      for (int off = 1; off < 16; off <<= 1)
        rsum[r] += __shfl_xor(rsum[r], off, 64);
      rsum[r] = 1.f / rsum[r];
    }
    #pragma unroll
    for (int ct = 0; ct < 7; ++ct)
      #pragma unroll
      for (int r = 0; r < 4; ++r)
        p_s[wid][g * 4 + r][ct * 16 + c16] = __float2bfloat16(sv[ct][r] * rsum[r]);

    asm volatile("s_waitcnt lgkmcnt(0)" ::: "memory");

    f32x4 o0 = vzero, o1 = vzero;
    #pragma unroll
    for (int kk = 0; kk < 4; ++kk) {
      bf16x8 pa = *(const bf16x8*)&p_s[wid][c16][kk * 32 + g * 8];
      bf16x8 v0 = *(const bf16x8*)&v_t[c16][kk * 32 + g * 8];
      bf16x8 v1 = *(const bf16x8*)&v_t[16 + c16][kk * 32 + g * 8];
      o0 = __builtin_amdgcn_mfma_f32_16x16x32_bf16(pa, v0, o0, 0, 0, 0);
      o1 = __builtin_amdgcn_mfma_f32_16x16x32_bf16(pa, v1, o1, 0, 0, 0);
    }
    #pragma unroll
    for (int r = 0; r < 4; ++r) {
      int qi = q0 + g * 4 + r;
      if (qi < 98) {
        size_t ob = (rowbase + qi) * 384 + head * 32;
        outp[ob + c16] = __float2bfloat16(o0[r]);
        outp[ob + 16 + c16] = __float2bfloat16(o1[r]);
      }
    }
  }
}

// ---------------------------------------------------------------------------
extern "C" void kernel_launch(void* const* d_in, const int* in_sizes, int n_in,
                              void* d_out, int out_size, void* d_ws, size_t ws_size,
                              hipStream_t stream)
{
  (void)in_sizes; (void)n_in; (void)out_size; (void)ws_size;
  const float* x      = (const float*)d_in[0];
  const float* t      = (const float*)d_in[1];
  const float* qkv_w  = (const float*)d_in[2];
  const float* qkv_b  = (const float*)d_in[3];
  const float* proj_w = (const float*)d_in[4];
  const float* proj_b = (const float*)d_in[5];
  const float* relb   = (const float*)d_in[6];
  const float* fc1_w  = (const float*)d_in[7];
  const float* fc1_b  = (const float*)d_in[8];
  const float* fc2_w  = (const float*)d_in[9];
  const float* fc2_b  = (const float*)d_in[10];
  const float* ada_w1 = (const float*)d_in[11];
  const float* ada_w2 = (const float*)d_in[12];
  const float* ada_b2 = (const float*)d_in[13];
  float* out = (float*)d_out;
  char* ws = (char*)d_ws;

  float* modbuf = (float*)(ws + 0);                     //   18,432 B
  bf16* wqkv_t  = (bf16*)(ws + 18432);                  //  884,736 B (frag-major)
  bf16* wproj_t = (bf16*)(ws + 903168);                 //  294,912 B
  bf16* wfc1_t  = (bf16*)(ws + 1198080);                // 1,179,648 B
  bf16* wfc2_t  = (bf16*)(ws + 2377728);                // 1,179,648 B
  bf16* bufA    = (bf16*)(ws + 3557376);                // 38,535,168 B (50176x384)
  bf16* qkvbuf  = (bf16*)(ws + 42092544);               // 115,605,504 B (50176x1152)
  bf16* bufB    = (bf16*)(ws + 42092544 + 115605504);   // 38,535,168 B
  bf16* midbuf  = (bf16*)(ws + 42092544);               // (50176x1536) reuses qkv+bufB
  bf16* bmbuf   = bufA;  // 1,204,224 B, lives in bufA region between qkv-GEMM and LN2

  // weights -> bf16 fragment-major
  wconv_frag_kernel<<<(384 * 1152 + 255) / 256, 256, 0, stream>>>(qkv_w, wqkv_t, 384, 1152);
  wconv_frag_kernel<<<(384 * 384 + 255) / 256, 256, 0, stream>>>(proj_w, wproj_t, 384, 384);
  wconv_frag_kernel<<<(384 * 1536 + 255) / 256, 256, 0, stream>>>(fc1_w, wfc1_t, 384, 1536);
  wconv_frag_kernel<<<(1536 * 384 + 255) / 256, 256, 0, stream>>>(fc2_w, wfc2_t, 1536, 384);

  mod_kernel<<<1, 256, 0, stream>>>(t, ada_w1, ada_w2, ada_b2, modbuf);

  // LN1 + modulate + roll + window partition -> bufA
  ln_mod_kernel<0><<<12544, 256, 0, stream>>>(x, modbuf, bufA);

  // QKV projection
  gemm128_kernel<0><<<dim3(9, 392), 256, 0, stream>>>(bufA, wqkv_t, qkv_b, 1152, 384,
                                                      qkvbuf, nullptr, nullptr, nullptr);

  // bias+mask table (into bufA region, free until LN2)
  bm_kernel<<<2352, 256, 0, stream>>>(relb, bmbuf);

  // window attention -> bufB
  attn_kernel<<<dim3(12, 512), 256, 0, stream>>>(qkvbuf, bmbuf, bufB);

  // proj + un-window + un-roll + residual
  gemm128_kernel<1><<<dim3(3, 392), 256, 0, stream>>>(bufB, wproj_t, proj_b, 384, 384,
                                                      nullptr, out, x, modbuf);

  // LN2 + modulate -> bufA
  ln_mod_kernel<1><<<12544, 256, 0, stream>>>(out, modbuf, bufA);

  // FC1 + gelu
  gemm128_kernel<2><<<dim3(12, 392), 256, 0, stream>>>(bufA, wfc1_t, fc1_b, 1536, 384,
                                                       midbuf, nullptr, nullptr, nullptr);

  // FC2 + residual
  gemm128_kernel<3><<<dim3(3, 392), 256, 0, stream>>>(midbuf, wfc2_t, fc2_b, 384, 1536,
                                                      nullptr, out, out, modbuf);
}

// Round 9
// 560.672 us; speedup vs baseline: 1.3034x; 1.3034x over previous
//
#include <hip/hip_runtime.h>
#include <hip/hip_bf16.h>
#include <math.h>

using bf16 = __hip_bfloat16;
typedef __bf16 bf16x8 __attribute__((ext_vector_type(8)));
typedef float f32x4 __attribute__((ext_vector_type(4)));
typedef unsigned int u32;

// B=2, D=8, H=56, W=56, C=384, NH=12, HD=32, WIN=(2,7,7), SHIFT=(1,3,3)
// N=98 tokens/window, 512 windows, rows = 50176

__device__ __forceinline__ void async_cp16(const void* g, void* l) {
  __builtin_amdgcn_global_load_lds(
      (const __attribute__((address_space(1))) u32*)g,
      (__attribute__((address_space(3))) u32*)l, 16, 0, 0);
}

// windowed row -> global token index (window-reverse + roll)
__device__ __forceinline__ int row_to_gidx(int row) {
  int win = row / 98, tok = row - win * 98;
  int b = win >> 8, wd = (win >> 6) & 3, wh = (win >> 3) & 7, ww = win & 7;
  int td = tok / 49, rem = tok - td * 49;
  int th = rem / 7, tw = rem - th * 7;
  int od = (wd * 2 + td + 1) & 7;
  int oh = wh * 7 + th + 3; if (oh >= 56) oh -= 56;
  int ow = ww * 7 + tw + 3; if (ow >= 56) ow -= 56;
  return ((b * 8 + od) * 56 + oh) * 56 + ow;
}

// ---------------- AdaLN modulation ------------------------------------------
__global__ __launch_bounds__(256) void mod_kernel(
    const float* __restrict__ t, const float* __restrict__ w1,
    const float* __restrict__ w2, const float* __restrict__ b2,
    float* __restrict__ modout)
{
  __shared__ float u[2 * 48];
  int tid = threadIdx.x;
  if (tid < 96) {
    int b = tid / 48, r = tid - (tid / 48) * 48;
    float acc = 0.f;
    for (int k = 0; k < 384; ++k) {
      float x = t[b * 384 + k];
      float s = x / (1.f + __expf(-x));
      acc += s * w1[k * 48 + r];
    }
    u[b * 48 + r] = acc;
  }
  __syncthreads();
  for (int idx = tid; idx < 2 * 2304; idx += 256) {
    int b = idx / 2304, c = idx - b * 2304;
    float acc = b2[c];
    #pragma unroll
    for (int k = 0; k < 48; ++k) acc += u[b * 48 + k] * w2[k * 2304 + c];
    modout[idx] = acc;
  }
}

// -------- weight convert f32 (K,N) -> bf16 MFMA-fragment-major layout -------
// Block (ntile = n>>4, kstep = k>>5) of 16 cols x 32 ks stored as 512 bf16:
// lane l = (n&15) + ((k>>3)&3)*16 holds elems j = k&7 at [block*512 + l*8 + j].
__global__ __launch_bounds__(256) void wconv_frag_kernel(
    const float* __restrict__ W, bf16* __restrict__ Wf, int K, int N)
{
  int idx = blockIdx.x * 256 + threadIdx.x;
  if (idx >= K * N) return;
  int k = idx / N, n = idx - (idx / N) * N;
  int ntile = n >> 4, kstep = k >> 5;
  int l = (n & 15) + (((k >> 3) & 3) << 4);
  size_t dst = (((size_t)(ntile * (K >> 5) + kstep)) << 9) + (l << 3) + (k & 7);
  Wf[dst] = __float2bfloat16(W[idx]);
}

// ---------------- bias+mask table: bm[4][12][112][112] bf16 -----------------
__global__ __launch_bounds__(256) void bm_kernel(
    const float* __restrict__ relb, bf16* __restrict__ bm)
{
  int idx = blockIdx.x * 256 + threadIdx.x;
  if (idx >= 4 * 12 * 112 * 112) return;
  int j = idx % 112, tmp = idx / 112;
  int i = tmp % 112; tmp /= 112;
  int h = tmp % 12, p = tmp / 12;
  float v;
  if (i < 98 && j < 98) {
    int tdi = i / 49, ri = i % 49, thi = ri / 7, twi = ri % 7;
    int tdj = j / 49, rj = j % 49, thj = rj / 7, twj = rj % 7;
    int ridx = (tdi - tdj + 1) * 169 + (thi - thj + 6) * 13 + (twi - twj + 6);
    bool msk = ((p & 2) && (tdi != tdj)) || ((p & 1) && ((thi < 4) != (thj < 4)));
    v = relb[ridx * 12 + h] + (msk ? -100.f : 0.f);
  } else {
    v = -1e38f;
  }
  bm[idx] = __float2bfloat16(v);
}

// ---------------- LN + modulate ---------------------------------------------
template <int PHASE>
__global__ __launch_bounds__(256) void ln_mod_kernel(
    const float* __restrict__ src, const float* __restrict__ modv,
    bf16* __restrict__ dst)
{
  int wid = threadIdx.x >> 6, lane = threadIdx.x & 63;
  int row = blockIdx.x * 4 + wid;
  int gtok;
  if (PHASE == 0) gtok = row_to_gidx(row); else gtok = row;
  int b = row / 25088;
  const float* s = src + (size_t)gtok * 384;
  float vals[6], sum = 0.f, sq = 0.f;
  #pragma unroll
  for (int i = 0; i < 6; ++i) {
    float v = s[lane + i * 64];
    vals[i] = v; sum += v; sq += v * v;
  }
  #pragma unroll
  for (int o = 32; o; o >>= 1) { sum += __shfl_xor(sum, o, 64); sq += __shfl_xor(sq, o, 64); }
  float mean = sum * (1.f / 384.f);
  float var = sq * (1.f / 384.f) - mean * mean;
  float rstd = rsqrtf(var + 1e-6f);
  int mb = b * 2304 + (PHASE == 0 ? 0 : 1152);
  #pragma unroll
  for (int i = 0; i < 6; ++i) {
    int c = lane + i * 64;
    float scv = modv[mb + 384 + c], shv = modv[mb + c];
    dst[(size_t)row * 384 + c] = __float2bfloat16((vals[i] - mean) * rstd * (1.f + scv) + shv);
  }
}

// ---------------- 128x128 bf16 MFMA GEMM ------------------------------------
// A staged in LDS via global_load_lds: 4 buffers (32KB), prefetch distance 2,
// counted vmcnt (never drains to 0 mid-loop), ONE barrier per K-step.
// B read directly from L2 in fragment-major layout (coalesced 1KB/wave).
// Safety: passing barrier(t-1) implies all waves finished compute(t-2), the
// previous tenant of buf[(t+2)&3]; vmcnt(4) = 2 loads x 2 younger stages
// guarantees tile t's loads retired (in-order retirement).
template <int EPI>
__global__ __launch_bounds__(256) void gemm128_kernel(
    const bf16* __restrict__ A, const bf16* __restrict__ Bf,
    const float* __restrict__ bias, const int N, const int K,
    bf16* __restrict__ outB, float* __restrict__ outF,
    const float* __restrict__ resid, const float* __restrict__ modv)
{
  __shared__ bf16 sA[4][128 * 32];
  const int tid = threadIdx.x;
  const int lane = tid & 63, wid = tid >> 6;
  const int wm = wid >> 1, wn = wid & 1;

  // XCD-contiguous remap (nwg % 8 == 0 for all our grids)
  const int gx = gridDim.x;
  const int nwg = gx * (int)gridDim.y;
  const int orig = (int)blockIdx.y * gx + (int)blockIdx.x;
  const int q = nwg >> 3;
  const int wg = (orig & 7) * q + (orig >> 3);
  const int bx = wg % gx, by = wg / gx;
  const int row0 = by * 128, col0 = bx * 128;

  const int lrow = lane & 15;
  const int sl8 = (((lane >> 4) ^ ((lane >> 1) & 3)) << 3);
  const int r0 = tid >> 2;
  const int c0 = (((tid & 3) ^ ((tid >> 3) & 3)) << 3);

  const int nK32 = K >> 5;
  const bf16* Bfb[4];
  #pragma unroll
  for (int n = 0; n < 4; ++n) {
    const int ntile = (col0 >> 4) + wn * 4 + n;
    Bfb[n] = Bf + (((size_t)(ntile * nK32)) << 9) + (lane << 3);
  }

  const f32x4 vzero = {0.f, 0.f, 0.f, 0.f};
  f32x4 acc[4][4];
  #pragma unroll
  for (int m = 0; m < 4; ++m)
    #pragma unroll
    for (int n = 0; n < 4; ++n) acc[m][n] = vzero;

  const bf16* Arow0 = A + (size_t)(row0 + r0) * K + c0;
  const bf16* Arow1 = A + (size_t)(row0 + r0 + 64) * K + c0;

  auto stage = [&](int b, int kt) {
    async_cp16(Arow0 + kt, &sA[b][(size_t)tid * 8]);
    async_cp16(Arow1 + kt, &sA[b][(size_t)(tid + 256) * 8]);
  };

  stage(0, 0);
  stage(1, 32);
  for (int t = 0; t < nK32; ++t) {
    if (t + 2 < nK32) stage((t + 2) & 3, (t + 2) * 32);
    const int younger = nK32 - 1 - t;  // stages issued after tile t's stage
    if (younger >= 2)      asm volatile("s_waitcnt vmcnt(4)" ::: "memory");
    else if (younger == 1) asm volatile("s_waitcnt vmcnt(2)" ::: "memory");
    else                   asm volatile("s_waitcnt vmcnt(0)" ::: "memory");
    __builtin_amdgcn_s_barrier();

    bf16x8 bfv[4], af[4];
    #pragma unroll
    for (int n = 0; n < 4; ++n)
      bfv[n] = *(const bf16x8*)(Bfb[n] + ((size_t)t << 9));
    #pragma unroll
    for (int m = 0; m < 4; ++m)
      af[m] = *(const bf16x8*)(&sA[t & 3][(wm * 64 + m * 16 + lrow) * 32 + sl8]);
    #pragma unroll
    for (int m = 0; m < 4; ++m)
      #pragma unroll
      for (int n = 0; n < 4; ++n)
        acc[m][n] = __builtin_amdgcn_mfma_f32_16x16x32_bf16(af[m], bfv[n], acc[m][n], 0, 0, 0);
  }

  #pragma unroll
  for (int m = 0; m < 4; ++m) {
    #pragma unroll
    for (int r = 0; r < 4; ++r) {
      const int row = row0 + wm * 64 + m * 16 + (lane >> 4) * 4 + r;
      int gofs = 0, b = 0;
      if (EPI == 1) { gofs = row_to_gidx(row) * 384; b = row / 25088; }
      if (EPI == 3) { gofs = row * 384; b = row / 25088; }
      #pragma unroll
      for (int n = 0; n < 4; ++n) {
        const int col = col0 + wn * 64 + n * 16 + (lane & 15);
        float v = acc[m][n][r] + bias[col];
        if (EPI == 0) {
          outB[(size_t)row * N + col] = __float2bfloat16(v);
        } else if (EPI == 2) {
          float g = 0.5f * v * (1.f + erff(v * 0.70710678118654752f));
          outB[(size_t)row * N + col] = __float2bfloat16(g);
        } else if (EPI == 1) {
          outF[gofs + col] = resid[gofs + col] + modv[b * 2304 + 768 + col] * v;
        } else {
          outF[gofs + col] = resid[gofs + col] + modv[b * 2304 + 1920 + col] * v;
        }
      }
    }
  }
}

// ---------------- MFMA window attention: block = (head, window) -------------
__global__ __launch_bounds__(256) void attn_kernel(
    const bf16* __restrict__ qkv, const bf16* __restrict__ bm,
    bf16* __restrict__ outp)
{
  __shared__ bf16 k_s[112][40];      // [token][d], zero rows >=98
  __shared__ bf16 v_t[32][136];      // [d][token], zero tokens 98..127
  __shared__ bf16 p_s[4][16][136];   // per-wave P strip, cols 112..135 zeroed

  const int head = blockIdx.x;
  const int win = blockIdx.y;
  const int tid = threadIdx.x;
  const int lane = tid & 63, wid = tid >> 6;
  const int g = lane >> 4, c16 = lane & 15;
  const size_t rowbase = (size_t)win * 98;
  const bf16 zero = __float2bfloat16(0.f);

  for (int lin = tid; lin < 448; lin += 256) {
    int row = lin >> 2, ch = (lin & 3) << 3;
    uint4 val = make_uint4(0, 0, 0, 0);
    if (row < 98)
      val = *(const uint4*)(qkv + (rowbase + row) * 1152 + 384 + head * 32 + ch);
    *(uint4*)&k_s[row][ch] = val;
  }
  for (int lin = tid; lin < 4096; lin += 256) {
    int d = lin & 31, tok = lin >> 5;
    bf16 val = zero;
    if (tok < 98) val = qkv[(rowbase + tok) * 1152 + 768 + head * 32 + d];
    v_t[d][tok] = val;
  }
  for (int lin = tid; lin < 1536; lin += 256) {
    int w = lin / 384, rem = lin - w * 384;
    p_s[w][rem / 24][112 + rem % 24] = zero;
  }
  __syncthreads();

  const int p = ((((win >> 6) & 3) == 3) ? 2 : 0) | ((((win >> 3) & 7) == 7) ? 1 : 0);
  const bf16* bmrow = bm + (size_t)(p * 12 + head) * 12544;
  const float scale = 0.17677669529663687f;  // 1/sqrt(32)
  const f32x4 vzero = {0.f, 0.f, 0.f, 0.f};

  for (int s = wid; s < 7; s += 4) {
    const int q0 = s * 16;
    int qrow = q0 + c16; if (qrow > 97) qrow = 97;
    bf16x8 qf = *(const bf16x8*)(qkv + (rowbase + qrow) * 1152 + head * 32 + g * 8);

    f32x4 sa[7];
    #pragma unroll
    for (int ct = 0; ct < 7; ++ct) {
      bf16x8 kf = *(const bf16x8*)&k_s[ct * 16 + c16][g * 8];
      sa[ct] = __builtin_amdgcn_mfma_f32_16x16x32_bf16(qf, kf, vzero, 0, 0, 0);
    }

    float sv[7][4];
    float mrow[4] = {-1e30f, -1e30f, -1e30f, -1e30f};
    #pragma unroll
    for (int ct = 0; ct < 7; ++ct) {
      #pragma unroll
      for (int r = 0; r < 4; ++r) {
        int i = q0 + g * 4 + r, j = ct * 16 + c16;
        float val = sa[ct][r] * scale + __bfloat162float(bmrow[i * 112 + j]);
        sv[ct][r] = val;
        mrow[r] = fmaxf(mrow[r], val);
      }
    }
    #pragma unroll
    for (int r = 0; r < 4; ++r) {
      #pragma unroll
      for (int off = 1; off < 16; off <<= 1)
        mrow[r] = fmaxf(mrow[r], __shfl_xor(mrow[r], off, 64));
    }
    float rsum[4] = {0.f, 0.f, 0.f, 0.f};
    #pragma unroll
    for (int ct = 0; ct < 7; ++ct) {
      #pragma unroll
      for (int r = 0; r < 4; ++r) {
        float e = __expf(sv[ct][r] - mrow[r]);
        sv[ct][r] = e;
        rsum[r] += e;
      }
    }
    #pragma unroll
    for (int r = 0; r < 4; ++r) {
      #pragma unroll
      for (int off = 1; off < 16; off <<= 1)
        rsum[r] += __shfl_xor(rsum[r], off, 64);
      rsum[r] = 1.f / rsum[r];
    }
    #pragma unroll
    for (int ct = 0; ct < 7; ++ct)
      #pragma unroll
      for (int r = 0; r < 4; ++r)
        p_s[wid][g * 4 + r][ct * 16 + c16] = __float2bfloat16(sv[ct][r] * rsum[r]);

    asm volatile("s_waitcnt lgkmcnt(0)" ::: "memory");

    f32x4 o0 = vzero, o1 = vzero;
    #pragma unroll
    for (int kk = 0; kk < 4; ++kk) {
      bf16x8 pa = *(const bf16x8*)&p_s[wid][c16][kk * 32 + g * 8];
      bf16x8 v0 = *(const bf16x8*)&v_t[c16][kk * 32 + g * 8];
      bf16x8 v1 = *(const bf16x8*)&v_t[16 + c16][kk * 32 + g * 8];
      o0 = __builtin_amdgcn_mfma_f32_16x16x32_bf16(pa, v0, o0, 0, 0, 0);
      o1 = __builtin_amdgcn_mfma_f32_16x16x32_bf16(pa, v1, o1, 0, 0, 0);
    }
    #pragma unroll
    for (int r = 0; r < 4; ++r) {
      int qi = q0 + g * 4 + r;
      if (qi < 98) {
        size_t ob = (rowbase + qi) * 384 + head * 32;
        outp[ob + c16] = __float2bfloat16(o0[r]);
        outp[ob + 16 + c16] = __float2bfloat16(o1[r]);
      }
    }
  }
}

// ---------------------------------------------------------------------------
extern "C" void kernel_launch(void* const* d_in, const int* in_sizes, int n_in,
                              void* d_out, int out_size, void* d_ws, size_t ws_size,
                              hipStream_t stream)
{
  (void)in_sizes; (void)n_in; (void)out_size; (void)ws_size;
  const float* x      = (const float*)d_in[0];
  const float* t      = (const float*)d_in[1];
  const float* qkv_w  = (const float*)d_in[2];
  const float* qkv_b  = (const float*)d_in[3];
  const float* proj_w = (const float*)d_in[4];
  const float* proj_b = (const float*)d_in[5];
  const float* relb   = (const float*)d_in[6];
  const float* fc1_w  = (const float*)d_in[7];
  const float* fc1_b  = (const float*)d_in[8];
  const float* fc2_w  = (const float*)d_in[9];
  const float* fc2_b  = (const float*)d_in[10];
  const float* ada_w1 = (const float*)d_in[11];
  const float* ada_w2 = (const float*)d_in[12];
  const float* ada_b2 = (const float*)d_in[13];
  float* out = (float*)d_out;
  char* ws = (char*)d_ws;

  float* modbuf = (float*)(ws + 0);                     //   18,432 B
  bf16* wqkv_t  = (bf16*)(ws + 18432);                  //  884,736 B (frag-major)
  bf16* wproj_t = (bf16*)(ws + 903168);                 //  294,912 B
  bf16* wfc1_t  = (bf16*)(ws + 1198080);                // 1,179,648 B
  bf16* wfc2_t  = (bf16*)(ws + 2377728);                // 1,179,648 B
  bf16* bufA    = (bf16*)(ws + 3557376);                // 38,535,168 B (50176x384)
  bf16* qkvbuf  = (bf16*)(ws + 42092544);               // 115,605,504 B (50176x1152)
  bf16* bufB    = (bf16*)(ws + 42092544 + 115605504);   // 38,535,168 B
  bf16* midbuf  = (bf16*)(ws + 42092544);               // (50176x1536) reuses qkv+bufB
  bf16* bmbuf   = bufA;  // 1,204,224 B, lives in bufA region between qkv-GEMM and LN2

  // weights -> bf16 fragment-major
  wconv_frag_kernel<<<(384 * 1152 + 255) / 256, 256, 0, stream>>>(qkv_w, wqkv_t, 384, 1152);
  wconv_frag_kernel<<<(384 * 384 + 255) / 256, 256, 0, stream>>>(proj_w, wproj_t, 384, 384);
  wconv_frag_kernel<<<(384 * 1536 + 255) / 256, 256, 0, stream>>>(fc1_w, wfc1_t, 384, 1536);
  wconv_frag_kernel<<<(1536 * 384 + 255) / 256, 256, 0, stream>>>(fc2_w, wfc2_t, 1536, 384);

  mod_kernel<<<1, 256, 0, stream>>>(t, ada_w1, ada_w2, ada_b2, modbuf);

  // LN1 + modulate + roll + window partition -> bufA
  ln_mod_kernel<0><<<12544, 256, 0, stream>>>(x, modbuf, bufA);

  // QKV projection
  gemm128_kernel<0><<<dim3(9, 392), 256, 0, stream>>>(bufA, wqkv_t, qkv_b, 1152, 384,
                                                      qkvbuf, nullptr, nullptr, nullptr);

  // bias+mask table (into bufA region, free until LN2)
  bm_kernel<<<2352, 256, 0, stream>>>(relb, bmbuf);

  // window attention -> bufB
  attn_kernel<<<dim3(12, 512), 256, 0, stream>>>(qkvbuf, bmbuf, bufB);

  // proj + un-window + un-roll + residual
  gemm128_kernel<1><<<dim3(3, 392), 256, 0, stream>>>(bufB, wproj_t, proj_b, 384, 384,
                                                      nullptr, out, x, modbuf);

  // LN2 + modulate -> bufA
  ln_mod_kernel<1><<<12544, 256, 0, stream>>>(out, modbuf, bufA);

  // FC1 + gelu
  gemm128_kernel<2><<<dim3(12, 392), 256, 0, stream>>>(bufA, wfc1_t, fc1_b, 1536, 384,
                                                       midbuf, nullptr, nullptr, nullptr);

  // FC2 + residual
  gemm128_kernel<3><<<dim3(3, 392), 256, 0, stream>>>(midbuf, wfc2_t, fc2_b, 384, 1536,
                                                      nullptr, out, out, modbuf);
}